// Round 4
// baseline (208.308 us; speedup 1.0000x reference)
//
#include <hip/hip_runtime.h>
#include <stdint.h>

// LIF forward scan: u = 0.5*u + x[t] - 0.5*o ; o = (u - 0.5 > 0) ? 1 : 0
// x: [32, 8192, 200] f32, time contiguous. 262144 independent rows.
//
// R4: wave-private double-buffered global_load_lds pipeline (T3/T4/T14).
//  - Each wave owns 64 rows + two 4KB LDS slices (16-step chunks).
//  - stage(chunk n+1) via 4x global_load_lds dwordx4 (no VGPR data regs ->
//    cannot spill, unlike R2), then s_waitcnt vmcnt(4): chunk n's staging is
//    guaranteed done while chunk n+1's loads stay in flight under the whole
//    compute+store phase. Loads in flight ~100% of the time per wave.
//  - gll writes LDS linearly (base + lane*16), so the SOURCE address is
//    pre-swizzled per lane: slot(r,c) = r*4 + (c ^ ((r>>1)&3)). The
//    compute-phase ds_read_b128 of row `lane` then hits all 32 banks
//    (minimal 8 words/bank).
//  - Spike stores are direct per-lane float4 (lane writes 64B contiguous
//    per chunk; L2 write-back merges partial sectors -> no HBM write amp),
//    removing the second LDS transpose.
//  - No __syncthreads anywhere (intra-wave cooperation only).
// Arithmetic uses __f*_rn to forbid FMA contraction (bit-exact vs numpy
// order; a spike flip near threshold is absmax=1.0).

#define STEPS 200
#define RPB 256

typedef __attribute__((address_space(3))) uint32_t lds_u32;
typedef __attribute__((address_space(1))) const uint32_t glb_u32;

#define WAITCNT(n) do { asm volatile("s_waitcnt vmcnt(" #n ")" ::: "memory"); \
                        __builtin_amdgcn_sched_barrier(0); } while (0)

__device__ __forceinline__ void lif_step(float& u, float& o, float xi) {
    float a = __fmul_rn(0.5f, u);
    float s = __fadd_rn(a, xi);
    float d = __fmul_rn(0.5f, o);
    u = __fsub_rn(s, d);
    o = (u > 0.5f) ? 1.0f : 0.0f;
}

// ---- staging: 16-step chunk = 4 gll insts; lane l feeds slot k*64+l ----
// slot s -> r = s>>2, c = (s&3) ^ ((r>>1)&3); for s=k*64+l this reduces to
// r = k*16 + (l>>2), c = (l&3) ^ ((l>>3)&3)  (lane-only -> one base addr).
__device__ __forceinline__ void stage16(const float* xlane, float4* slice, int t0) {
#pragma unroll
    for (int k = 0; k < 4; ++k)
        __builtin_amdgcn_global_load_lds((const glb_u32*)(xlane + k * 16 * STEPS + t0),
                                         (lds_u32*)(slice + k * 64), 16, 0, 0);
}

// ---- staging: 8-step tail = 2 gll insts; r = k*32 + (l>>1), c = (l&1)^((l>>1)&1)
__device__ __forceinline__ void stage8(const float* xlaneT, float4* slice, int t0) {
#pragma unroll
    for (int k = 0; k < 2; ++k)
        __builtin_amdgcn_global_load_lds((const glb_u32*)(xlaneT + k * 32 * STEPS + t0),
                                         (lds_u32*)(slice + k * 64), 16, 0, 0);
}

// ---- compute 16 steps from slice (row = lane), direct float4 spike stores ----
__device__ __forceinline__ void chunk16(const float4* buf, float* olane, int lane,
                                        int t0, float& u, float& o) {
    const int sw = (lane >> 1) & 3;
    float4 rx[4];
#pragma unroll
    for (int c = 0; c < 4; ++c)
        rx[c] = buf[lane * 4 + (c ^ sw)];
#pragma unroll
    for (int c = 0; c < 4; ++c) {
        float4 f4 = rx[c];
        lif_step(u, o, f4.x); float o0 = o;
        lif_step(u, o, f4.y); float o1 = o;
        lif_step(u, o, f4.z); float o2 = o;
        lif_step(u, o, f4.w); float o3 = o;
        *reinterpret_cast<float4*>(olane + t0 + c * 4) = make_float4(o0, o1, o2, o3);
    }
}

__device__ __forceinline__ void chunk8(const float4* buf, float* olane, int lane,
                                       int t0, float& u, float& o) {
    const int sw = lane & 1;
    float4 rx[2];
#pragma unroll
    for (int c = 0; c < 2; ++c)
        rx[c] = buf[lane * 2 + (c ^ sw)];
#pragma unroll
    for (int c = 0; c < 2; ++c) {
        float4 f4 = rx[c];
        lif_step(u, o, f4.x); float o0 = o;
        lif_step(u, o, f4.y); float o1 = o;
        lif_step(u, o, f4.z); float o2 = o;
        lif_step(u, o, f4.w); float o3 = o;
        *reinterpret_cast<float4*>(olane + t0 + c * 4) = make_float4(o0, o1, o2, o3);
    }
}

__global__ __launch_bounds__(RPB) void lif_kernel(
    const float* __restrict__ x, float* __restrict__ out)
{
    __shared__ float4 tile[2048];          // 4 waves x 2 bufs x 256 slots = 32 KB
    const int tid  = threadIdx.x;
    const int w    = tid >> 6;
    const int lane = tid & 63;
    const long long row0 = (long long)blockIdx.x * RPB + w * 64;
    const float* xb = x + row0 * STEPS;
    float* ob = out + row0 * STEPS;
    float4* bufA = &tile[(w * 2 + 0) * 256];
    float4* bufB = &tile[(w * 2 + 1) * 256];

    // pre-swizzled per-lane global source bases (see stage16/stage8 derivations)
    const float* xlane  = xb + (lane >> 2) * STEPS + (((lane & 3) ^ ((lane >> 3) & 3)) << 2);
    const float* xlaneT = xb + (lane >> 1) * STEPS + (((lane & 1) ^ ((lane >> 1) & 1)) << 2);
    float* olane = ob + lane * STEPS;

    float u = 0.0f, o = 0.0f;

    stage16(xlane, bufA, 0);               // prologue: chunk 0 -> bufA
#pragma unroll
    for (int ch = 0; ch < 12; ++ch) {
        float4* cur = (ch & 1) ? bufB : bufA;
        float4* nxt = (ch & 1) ? bufA : bufB;
        if (ch < 11) {
            stage16(xlane, nxt, (ch + 1) * 16);   // prefetch next chunk
            WAITCNT(4);                           // cur staged; 4 new gll stay in flight
        } else {
            stage8(xlaneT, nxt, 192);             // prefetch tail
            WAITCNT(2);
        }
        chunk16(cur, olane, lane, ch * 16, u, o);
    }
    WAITCNT(0);                                    // tail staged (ch=12 -> bufA)
    chunk8(bufA, olane, lane, 192, u, o);
}

extern "C" void kernel_launch(void* const* d_in, const int* in_sizes, int n_in,
                              void* d_out, int out_size, void* d_ws, size_t ws_size,
                              hipStream_t stream)
{
    const float* x = (const float*)d_in[0];
    float* out = (float*)d_out;
    int nrows = in_sizes[0] / STEPS;   // 262144
    int grid = nrows / RPB;            // 1024 blocks = 4 per CU, exact
    lif_kernel<<<grid, RPB, 0, stream>>>(x, out);
}

// Round 5
// 147.334 us; speedup vs baseline: 1.4139x; 1.4139x over previous
//
#include <hip/hip_runtime.h>

// LIF forward scan: u = 0.5*u + x[t] - 0.5*o ; o = (u - 0.5 > 0) ? 1 : 0
// x: [32, 8192, 200] f32, time contiguous. 262144 independent rows.
//
// R5: direct, no-LDS, register ping-pong pipeline.
//  - One row per lane (4096 waves, 16/CU). No LDS, no barriers, no staging.
//  - Two named register buffers A/B of 8 float4 (constant indices only ->
//    guaranteed registers, not scratch). While group g computes out of one
//    buffer, the 8 loads of group g+1 are in flight into the other ->
//    ~8KB/wave in flight ~100% of the time (~128KB/CU), vs R1-R4's one
//    batch per chunk (the measured 2.4 TB/s ceiling).
//  - sched_barrier(0) after each load burst pins loads above the following
//    compute (stops the scheduler sinking them to reduce pressure, which
//    is what killed R2).
//  - Per-lane 16B loads at 800B row stride: each lane consumes its row
//    sequentially, so every 128B line is fully used within ~8 consecutive
//    wave-insts (L1-resident reuse window) -> no HBM over-fetch expected.
//  - Stores are fire-and-forget; buffer registers are reused a full group
//    later, so no store-retire stalls (R4's bug).
// Arithmetic uses __f*_rn to forbid FMA contraction (bit-exact vs numpy
// order; a spike flip near threshold is absmax=1.0).

#define STEPS 200
#define RPB 256

#define SB() __builtin_amdgcn_sched_barrier(0)

__device__ __forceinline__ void lif_step(float& u, float& o, float xi) {
    float a = __fmul_rn(0.5f, u);
    float s = __fadd_rn(a, xi);
    float d = __fmul_rn(0.5f, o);
    u = __fsub_rn(s, d);
    o = (u > 0.5f) ? 1.0f : 0.0f;
}

template <int NF4>
__device__ __forceinline__ void loadN(float4* b, const float* __restrict__ xr, int t0) {
#pragma unroll
    for (int k = 0; k < NF4; ++k)
        b[k] = *reinterpret_cast<const float4*>(xr + t0 + k * 4);
}

template <int NF4>
__device__ __forceinline__ void compN(const float4* b, float* __restrict__ orow,
                                      int t0, float& u, float& o) {
#pragma unroll
    for (int k = 0; k < NF4; ++k) {
        float4 f4 = b[k];
        lif_step(u, o, f4.x); float o0 = o;
        lif_step(u, o, f4.y); float o1 = o;
        lif_step(u, o, f4.z); float o2 = o;
        lif_step(u, o, f4.w); float o3 = o;
        *reinterpret_cast<float4*>(orow + t0 + k * 4) = make_float4(o0, o1, o2, o3);
    }
}

__global__ __launch_bounds__(RPB, 4) void lif_kernel(
    const float* __restrict__ x, float* __restrict__ out)
{
    const long long row = (long long)blockIdx.x * RPB + threadIdx.x;
    const float* xr = x + row * STEPS;
    float* orow = out + row * STEPS;
    float u = 0.0f, o = 0.0f;

    float4 A[8], B[8];                 // named ping-pong buffers, const-indexed

    loadN<8>(A, xr, 0);   SB();
    loadN<8>(B, xr, 32);  SB();        // depth-1 prefetch established
    compN<8>(A, orow, 0, u, o);
    loadN<8>(A, xr, 64);  SB();
    compN<8>(B, orow, 32, u, o);
    loadN<8>(B, xr, 96);  SB();
    compN<8>(A, orow, 64, u, o);
    loadN<8>(A, xr, 128); SB();
    compN<8>(B, orow, 96, u, o);
    loadN<8>(B, xr, 160); SB();
    compN<8>(A, orow, 128, u, o);
    loadN<2>(A, xr, 192); SB();        // tail: steps 192..199
    compN<8>(B, orow, 160, u, o);
    compN<2>(A, orow, 192, u, o);
}

extern "C" void kernel_launch(void* const* d_in, const int* in_sizes, int n_in,
                              void* d_out, int out_size, void* d_ws, size_t ws_size,
                              hipStream_t stream)
{
    const float* x = (const float*)d_in[0];
    float* out = (float*)d_out;
    int nrows = in_sizes[0] / STEPS;   // 262144
    int grid = nrows / RPB;            // 1024 blocks, 4 per CU
    lif_kernel<<<grid, RPB, 0, stream>>>(x, out);
}